// Round 4
// baseline (401.089 us; speedup 1.0000x reference)
//
#include <hip/hip_runtime.h>

// MultiHeadAttention: B=2, N=2048, C=768, H=12, DH=64. fp32 in/out, bf16 MFMA compute.
// R4: attn waves key-sliced (64q block, 32-key slice per wave) -> LDS fragment
// traffic 4x down; cross-wave O reduction in bf16 via reused K/V LDS.
// GEMMs: BK=64 (half the barriers).

typedef __bf16 bf16_t;
typedef __bf16 bf16x8 __attribute__((ext_vector_type(8)));
typedef __bf16 bf16x4 __attribute__((ext_vector_type(4)));
typedef short  short4_t __attribute__((ext_vector_type(4)));
typedef float  floatx4 __attribute__((ext_vector_type(4)));

#define MFMA32(a, b, c) __builtin_amdgcn_mfma_f32_16x16x32_bf16(a, b, c, 0, 0, 0)
#define MFMA16(a, b, c) __builtin_amdgcn_mfma_f32_16x16x16bf16_1k(a, b, c, 0, 0, 0)

// ---------------------------------------------------------------- converts --
__global__ __launch_bounds__(256) void cvt_x_kernel(const float* __restrict__ x,
                                                    bf16_t* __restrict__ xb) {
  int i = blockIdx.x * 256 + threadIdx.x;
  floatx4 v = ((const floatx4*)x)[i];
  bf16x4 o;
  o[0] = (bf16_t)v[0]; o[1] = (bf16_t)v[1]; o[2] = (bf16_t)v[2]; o[3] = (bf16_t)v[3];
  ((bf16x4*)xb)[i] = o;
}

// W [in=768][out=768] fp32 -> WT [out][in] bf16; blockIdx.z picks which matrix.
__global__ __launch_bounds__(256) void cvt_wt_kernel(
    const float* __restrict__ W0, const float* __restrict__ W1,
    const float* __restrict__ W2, const float* __restrict__ W3,
    bf16_t* __restrict__ T0, bf16_t* __restrict__ T1,
    bf16_t* __restrict__ T2, bf16_t* __restrict__ T3) {
  const int z = blockIdx.z;
  const float* W = (z == 0) ? W0 : (z == 1) ? W1 : (z == 2) ? W2 : W3;
  bf16_t* WT = (z == 0) ? T0 : (z == 1) ? T1 : (z == 2) ? T2 : T3;
  __shared__ bf16_t T[64][65];
  const int c = threadIdx.x & 63, r0 = threadIdx.x >> 6;
  const int i0 = blockIdx.y * 64, o0 = blockIdx.x * 64;
#pragma unroll
  for (int p = 0; p < 16; ++p) {
    int r = p * 4 + r0;
    T[r][c] = (bf16_t)W[(i0 + r) * 768 + o0 + c];
  }
  __syncthreads();
#pragma unroll
  for (int p = 0; p < 16; ++p) {
    int r = p * 4 + r0;
    WT[(o0 + r) * 768 + i0 + c] = T[c][r];
  }
}

// ------------------------------------------------------------------- GEMMs --
#define LDPG 72  // BK=64 + 8 pad

// Fused QKV, M = output channels (768), N = tokens (4096).
__global__ __launch_bounds__(256) void gemm_qkv(
    const bf16_t* __restrict__ Xb, const bf16_t* __restrict__ WqT,
    const bf16_t* __restrict__ WkT, const bf16_t* __restrict__ WvT,
    const float* __restrict__ bq, const float* __restrict__ bk,
    const float* __restrict__ bv, bf16_t* __restrict__ qw,
    bf16_t* __restrict__ kw, bf16_t* __restrict__ vtw) {
  __shared__ bf16_t Al[128 * LDPG];
  __shared__ bf16_t Bl[128 * LDPG];
  const int z = blockIdx.z;
  const bf16_t* Wt = (z == 0) ? WqT : (z == 1) ? WkT : WvT;
  const float* bias = (z == 0) ? bq : (z == 1) ? bk : bv;
  const float oscale = (z == 0) ? 0.18033688011112042f : 1.0f;  // 0.125*log2(e)

  const int tid = threadIdx.x, lane = tid & 63, w = tid >> 6;
  const int wr = w >> 1, wc = w & 1;
  const int l15 = lane & 15, quad = lane >> 4;
  const int m0 = blockIdx.y * 128, n0 = blockIdx.x * 128;

  floatx4 acc[4][4] = {};

  for (int kt = 0; kt < 768; kt += 64) {
#pragma unroll
    for (int p = 0; p < 4; ++p) {
      int c = p * 256 + tid;
      int row = c >> 3, qo = (c & 7) * 8;
      *(bf16x8*)&Al[row * LDPG + qo] = *(const bf16x8*)&Wt[(m0 + row) * 768 + kt + qo];
      *(bf16x8*)&Bl[row * LDPG + qo] = *(const bf16x8*)&Xb[(n0 + row) * 768 + kt + qo];
    }
    __syncthreads();
#pragma unroll
    for (int kk = 0; kk < 2; ++kk) {
      bf16x8 af[4], bfr[4];
#pragma unroll
      for (int i = 0; i < 4; ++i) {
        af[i]  = *(bf16x8*)&Al[(wr * 64 + i * 16 + l15) * LDPG + kk * 32 + quad * 8];
        bfr[i] = *(bf16x8*)&Bl[(wc * 64 + i * 16 + l15) * LDPG + kk * 32 + quad * 8];
      }
#pragma unroll
      for (int mi = 0; mi < 4; ++mi)
#pragma unroll
        for (int ni = 0; ni < 4; ++ni)
          acc[mi][ni] = MFMA32(af[mi], bfr[ni], acc[mi][ni]);
    }
    __syncthreads();
  }

  const int hh = (m0 + wr * 64) >> 6;
#pragma unroll
  for (int mi = 0; mi < 4; ++mi) {
    const int d0 = mi * 16 + quad * 4;
    const int gm0 = m0 + wr * 64 + d0;
    float bv4[4];
#pragma unroll
    for (int r = 0; r < 4; ++r) bv4[r] = bias[gm0 + r];
#pragma unroll
    for (int ni = 0; ni < 4; ++ni) {
      const int gn = n0 + wc * 64 + ni * 16 + l15;
      const int bb = gn >> 11, tok = gn & 2047;
      if (z < 2) {
        bf16_t* o = (z == 0) ? qw : kw;
        bf16x4 pk;
#pragma unroll
        for (int r = 0; r < 4; ++r)
          pk[r] = (bf16_t)((acc[mi][ni][r] + bv4[r]) * oscale);
        *(bf16x4*)&o[(((bb * 12 + hh) * 2048 + tok) << 6) + d0] = pk;
      } else {
#pragma unroll
        for (int r = 0; r < 4; ++r)
          vtw[(((bb * 12 + hh) << 6) + d0 + r) * 2048 + tok] =
              (bf16_t)(acc[mi][ni][r] + bv4[r]);
      }
    }
  }
}

// Output projection, M = channels: out fp32 [4096 tok][768 ch] via float4 stores.
__global__ __launch_bounds__(256) void gemm_proj(
    const bf16_t* __restrict__ Yb, const bf16_t* __restrict__ WpT,
    const float* __restrict__ bias, float* __restrict__ out) {
  __shared__ bf16_t Al[128 * LDPG];
  __shared__ bf16_t Bl[128 * LDPG];
  const int tid = threadIdx.x, lane = tid & 63, w = tid >> 6;
  const int wr = w >> 1, wc = w & 1;
  const int l15 = lane & 15, quad = lane >> 4;
  const int m0 = blockIdx.y * 128, n0 = blockIdx.x * 128;

  floatx4 acc[4][4] = {};

  for (int kt = 0; kt < 768; kt += 64) {
#pragma unroll
    for (int p = 0; p < 4; ++p) {
      int c = p * 256 + tid;
      int row = c >> 3, qo = (c & 7) * 8;
      *(bf16x8*)&Al[row * LDPG + qo] = *(const bf16x8*)&WpT[(m0 + row) * 768 + kt + qo];
      *(bf16x8*)&Bl[row * LDPG + qo] = *(const bf16x8*)&Yb[(n0 + row) * 768 + kt + qo];
    }
    __syncthreads();
#pragma unroll
    for (int kk = 0; kk < 2; ++kk) {
      bf16x8 af[4], bfr[4];
#pragma unroll
      for (int i = 0; i < 4; ++i) {
        af[i]  = *(bf16x8*)&Al[(wr * 64 + i * 16 + l15) * LDPG + kk * 32 + quad * 8];
        bfr[i] = *(bf16x8*)&Bl[(wc * 64 + i * 16 + l15) * LDPG + kk * 32 + quad * 8];
      }
#pragma unroll
      for (int mi = 0; mi < 4; ++mi)
#pragma unroll
        for (int ni = 0; ni < 4; ++ni)
          acc[mi][ni] = MFMA32(af[mi], bfr[ni], acc[mi][ni]);
    }
    __syncthreads();
  }

#pragma unroll
  for (int mi = 0; mi < 4; ++mi) {
    const int gm0 = m0 + wr * 64 + mi * 16 + quad * 4;
    floatx4 bv4;
#pragma unroll
    for (int r = 0; r < 4; ++r) bv4[r] = bias[gm0 + r];
#pragma unroll
    for (int ni = 0; ni < 4; ++ni) {
      const int gn = n0 + wc * 64 + ni * 16 + l15;
      floatx4 v = acc[mi][ni] + bv4;
      *(floatx4*)&out[gn * 768 + gm0] = v;
    }
  }
}

// --------------------------------------------------------------- attention --
// Block: one (b,h), 64 Q rows.  Each wave computes ALL 64 q x its PRIVATE
// 32-key slice of every 128-key tile (Q in registers).  LDS frag reads: K 4KB +
// V 4KB per wave per tile.  S^T = K*Q^T so P lands in x16 A-frag layout.
// End: cross-wave O reduction (bf16, reuses K/V LDS) + lsum exchange.
__global__ __launch_bounds__(256) void attn_kernel(
    const bf16_t* __restrict__ Q, const bf16_t* __restrict__ Kg,
    const bf16_t* __restrict__ Vt, bf16_t* __restrict__ Y) {
  constexpr int AKP = 72, AVP = 136;
  __shared__ __align__(16) char smem[128 * AKP * 2 + 64 * AVP * 2];  // 35840 B
  bf16_t* Kl = (bf16_t*)smem;                 // [128 key][AKP]
  bf16_t* Vl = (bf16_t*)(smem + 128 * AKP * 2);  // [64 d][AVP]
  bf16_t* Ox = (bf16_t*)smem;                 // exchange: [nd][src][ni][256] bf16 (32KB)
  float*  Ls = (float*)(smem + 32768);        // [src][ni][16] (1KB)

  const int tid = threadIdx.x, lane = tid & 63, w = tid >> 6;
  const int l15 = lane & 15, quad = lane >> 4;
  const int bh = blockIdx.y;
  const int q0 = blockIdx.x * 64;
  const bf16_t* Qb = Q + bh * 2048 * 64;
  const bf16_t* Kb = Kg + bh * 2048 * 64;
  const bf16_t* Vb = Vt + bh * 64 * 2048;

  // Q B-frags (x32): n=q over l15, k=dh over quad*8+j; all 64 q in regs.
  bf16x8 qf[4][2];
#pragma unroll
  for (int ni = 0; ni < 4; ++ni)
#pragma unroll
    for (int kk = 0; kk < 2; ++kk)
      qf[ni][kk] = *(const bf16x8*)&Qb[(q0 + ni * 16 + l15) * 64 + kk * 32 + quad * 8];

  floatx4 oacc[4][4] = {};       // [ni(q16)][nd(d16)]
  float lsum[4] = {0.f, 0.f, 0.f, 0.f};  // per-lane partial for q=ni*16+l15

  for (int kt = 0; kt < 16; ++kt) {
    const int key0 = kt * 128;
#pragma unroll
    for (int p = 0; p < 4; ++p) {
      int c = p * 256 + tid;
      int kr = c >> 3, kq = (c & 7) * 8;
      *(bf16x8*)&Kl[kr * AKP + kq] = *(const bf16x8*)&Kb[(key0 + kr) * 64 + kq];
      int vr = c >> 4, vq = (c & 15) * 8;
      *(bf16x8*)&Vl[vr * AVP + vq] = *(const bf16x8*)&Vb[vr * 2048 + key0 + vq];
    }
    __syncthreads();

    // S^T for this wave's 32 keys x 64 q: A = K rows (m=key), B = qf.
    floatx4 s[2][4] = {};
#pragma unroll
    for (int mt = 0; mt < 2; ++mt)
#pragma unroll
      for (int kk = 0; kk < 2; ++kk) {
        bf16x8 kf = *(bf16x8*)&Kl[(w * 32 + mt * 16 + l15) * AKP + kk * 32 + quad * 8];
#pragma unroll
        for (int ni = 0; ni < 4; ++ni)
          s[mt][ni] = MFMA32(kf, qf[ni][kk], s[mt][ni]);
      }

    // P = exp2(S); pack to x16 A-frags; per-lane row-sum partials.
    short4_t pk[2][4];
#pragma unroll
    for (int mt = 0; mt < 2; ++mt)
#pragma unroll
      for (int ni = 0; ni < 4; ++ni) {
        bf16x4 ph;
#pragma unroll
        for (int r = 0; r < 4; ++r) {
          const float pv = __builtin_amdgcn_exp2f(s[mt][ni][r]);
          lsum[ni] += pv;
          ph[r] = (bf16_t)pv;
        }
        pk[mt][ni] = __builtin_bit_cast(short4_t, ph);
      }

    // O += P*V (x16): V B-frag reused across 4 q-tiles.
#pragma unroll
    for (int mt = 0; mt < 2; ++mt)
#pragma unroll
      for (int nd = 0; nd < 4; ++nd) {
        bf16x4 vf = *(bf16x4*)&Vl[(nd * 16 + l15) * AVP + w * 32 + mt * 16 + quad * 4];
        short4_t vs = __builtin_bit_cast(short4_t, vf);
#pragma unroll
        for (int ni = 0; ni < 4; ++ni)
          oacc[ni][nd] = MFMA16(pk[mt][ni], vs, oacc[ni][nd]);
      }
    __syncthreads();
  }

  // lsum: reduce across quads -> lane holds total-for-this-wave for q=ni*16+l15.
#pragma unroll
  for (int ni = 0; ni < 4; ++ni) {
    lsum[ni] += __shfl_xor(lsum[ni], 16);
    lsum[ni] += __shfl_xor(lsum[ni], 32);
  }

  // Cross-wave exchange (reuses K/V LDS; last barrier of loop protects reads).
#pragma unroll
  for (int ni = 0; ni < 4; ++ni)
#pragma unroll
    for (int nd = 0; nd < 4; ++nd) {
      bf16x4 ob;
#pragma unroll
      for (int r = 0; r < 4; ++r) ob[r] = (bf16_t)oacc[ni][nd][r];
      *(bf16x4*)&Ox[(((nd * 4 + w) * 4 + ni) * 64 + lane) * 4] = ob;
    }
  if (quad == 0) {
#pragma unroll
    for (int ni = 0; ni < 4; ++ni) Ls[(w * 4 + ni) * 16 + l15] = lsum[ni];
  }
  __syncthreads();

  // Wave w owns d-quarter nd=w: sum 4 partials, normalize, store.
  const int bb = bh / 12, h = bh % 12;
  const int col = h * 64 + w * 16 + l15;
#pragma unroll
  for (int ni = 0; ni < 4; ++ni) {
    floatx4 ofin = oacc[ni][w];
#pragma unroll
    for (int src = 0; src < 4; ++src) {
      if (src == w) continue;
      bf16x4 ob = *(bf16x4*)&Ox[(((w * 4 + src) * 4 + ni) * 64 + lane) * 4];
#pragma unroll
      for (int r = 0; r < 4; ++r) ofin[r] += (float)ob[r];
    }
#pragma unroll
    for (int r = 0; r < 4; ++r) {
      const float tot = Ls[(0 * 4 + ni) * 16 + quad * 4 + r] +
                        Ls[(1 * 4 + ni) * 16 + quad * 4 + r] +
                        Ls[(2 * 4 + ni) * 16 + quad * 4 + r] +
                        Ls[(3 * 4 + ni) * 16 + quad * 4 + r];
      const int tok = q0 + ni * 16 + quad * 4 + r;
      Y[(bb * 2048 + tok) * 768 + col] = (bf16_t)(ofin[r] / tot);
    }
  }
}

// ------------------------------------------------------------------ launch --
extern "C" void kernel_launch(void* const* d_in, const int* in_sizes, int n_in,
                              void* d_out, int out_size, void* d_ws, size_t ws_size,
                              hipStream_t stream) {
  const float* x  = (const float*)d_in[0];
  const float* Wq = (const float*)d_in[1];
  const float* bq = (const float*)d_in[2];
  const float* Wk = (const float*)d_in[3];
  const float* bk = (const float*)d_in[4];
  const float* Wv = (const float*)d_in[5];
  const float* bv = (const float*)d_in[6];
  const float* Wp = (const float*)d_in[7];
  const float* bp = (const float*)d_in[8];
  float* out = (float*)d_out;

  char* ws = (char*)d_ws;
  bf16_t* xb  = (bf16_t*)ws; ws += (size_t)4096 * 768 * 2;
  bf16_t* WqT = (bf16_t*)ws; ws += (size_t)768 * 768 * 2;
  bf16_t* WkT = (bf16_t*)ws; ws += (size_t)768 * 768 * 2;
  bf16_t* WvT = (bf16_t*)ws; ws += (size_t)768 * 768 * 2;
  bf16_t* WpT = (bf16_t*)ws; ws += (size_t)768 * 768 * 2;
  bf16_t* qw  = (bf16_t*)ws; ws += (size_t)24 * 2048 * 64 * 2;
  bf16_t* kw  = (bf16_t*)ws; ws += (size_t)24 * 2048 * 64 * 2;
  bf16_t* vtw = (bf16_t*)ws; ws += (size_t)24 * 2048 * 64 * 2;
  bf16_t* yw  = (bf16_t*)ws; ws += (size_t)4096 * 768 * 2;

  cvt_x_kernel<<<3072, 256, 0, stream>>>(x, xb);
  cvt_wt_kernel<<<dim3(12, 12, 4), 256, 0, stream>>>(Wq, Wk, Wv, Wp, WqT, WkT, WvT, WpT);

  gemm_qkv<<<dim3(32, 6, 3), 256, 0, stream>>>(xb, WqT, WkT, WvT, bq, bk, bv, qw, kw, vtw);
  attn_kernel<<<dim3(32, 24), 256, 0, stream>>>(qw, kw, vtw, yw);
  gemm_proj<<<dim3(32, 6), 256, 0, stream>>>(yw, WpT, bp, out);
}

// Round 5
// 190.087 us; speedup vs baseline: 2.1100x; 2.1100x over previous
//
#include <hip/hip_runtime.h>

// MultiHeadAttention: B=2, N=2048, C=768, H=12, DH=64. fp32 in/out, bf16 MFMA compute.
// R5: attn waves split 2(q) x 2(key-half) -> frag traffic halved, state ~100 VGPR
// (R4 spilled at 64q/wave).  K/V stored in MFMA-fragment order in global so attn
// staging is linear (conflict-free) and ALL fragment reads are lane-contiguous
// (zero bank conflicts, no padding).  Cross-wave O reduction (fp32) via reused LDS.

typedef __bf16 bf16_t;
typedef __bf16 bf16x8 __attribute__((ext_vector_type(8)));
typedef __bf16 bf16x4 __attribute__((ext_vector_type(4)));
typedef short  short4_t __attribute__((ext_vector_type(4)));
typedef float  floatx4 __attribute__((ext_vector_type(4)));

#define MFMA32(a, b, c) __builtin_amdgcn_mfma_f32_16x16x32_bf16(a, b, c, 0, 0, 0)
#define MFMA16(a, b, c) __builtin_amdgcn_mfma_f32_16x16x16bf16_1k(a, b, c, 0, 0, 0)

// ---------------------------------------------------------------- converts --
__global__ __launch_bounds__(256) void cvt_x_kernel(const float* __restrict__ x,
                                                    bf16_t* __restrict__ xb) {
  int i = blockIdx.x * 256 + threadIdx.x;
  floatx4 v = ((const floatx4*)x)[i];
  bf16x4 o;
  o[0] = (bf16_t)v[0]; o[1] = (bf16_t)v[1]; o[2] = (bf16_t)v[2]; o[3] = (bf16_t)v[3];
  ((bf16x4*)xb)[i] = o;
}

// W [in=768][out=768] fp32 -> WT [out][in] bf16; blockIdx.z picks which matrix.
__global__ __launch_bounds__(256) void cvt_wt_kernel(
    const float* __restrict__ W0, const float* __restrict__ W1,
    const float* __restrict__ W2, const float* __restrict__ W3,
    bf16_t* __restrict__ T0, bf16_t* __restrict__ T1,
    bf16_t* __restrict__ T2, bf16_t* __restrict__ T3) {
  const int z = blockIdx.z;
  const float* W = (z == 0) ? W0 : (z == 1) ? W1 : (z == 2) ? W2 : W3;
  bf16_t* WT = (z == 0) ? T0 : (z == 1) ? T1 : (z == 2) ? T2 : T3;
  __shared__ bf16_t T[64][65];
  const int c = threadIdx.x & 63, r0 = threadIdx.x >> 6;
  const int i0 = blockIdx.y * 64, o0 = blockIdx.x * 64;
#pragma unroll
  for (int p = 0; p < 16; ++p) {
    int r = p * 4 + r0;
    T[r][c] = (bf16_t)W[(i0 + r) * 768 + o0 + c];
  }
  __syncthreads();
#pragma unroll
  for (int p = 0; p < 16; ++p) {
    int r = p * 4 + r0;
    WT[(o0 + r) * 768 + i0 + c] = T[c][r];
  }
}

// ------------------------------------------------------------------- GEMMs --
#define LDPG 72  // BK=64 + 8 pad

// Fragment-order layouts (per bh = b*12+h, per 128-key tile kt):
//  K: elem(key,d) -> kt*8192 + ((nk*2+kk)*64 + quad*16 + l15)*8 + j
//     nk=key128>>4, l15=key128&15, kk=d>>5, quad=(d>>3)&3, j=d&7
//  V: elem(key,d) -> kt*8192 + ((nk*4+nd)*64 + vq*16 + vl15)*4 + j
//     nk=key128>>4, vq=(key128>>2)&3, j=key128&3, nd=d>>4, vl15=d&15

// Fused QKV, M = output channels (768), N = tokens (4096).
__global__ __launch_bounds__(256) void gemm_qkv(
    const bf16_t* __restrict__ Xb, const bf16_t* __restrict__ WqT,
    const bf16_t* __restrict__ WkT, const bf16_t* __restrict__ WvT,
    const float* __restrict__ bq, const float* __restrict__ bk,
    const float* __restrict__ bv, bf16_t* __restrict__ qw,
    bf16_t* __restrict__ kw, bf16_t* __restrict__ vtw) {
  __shared__ bf16_t Al[128 * LDPG];
  __shared__ bf16_t Bl[128 * LDPG];
  const int z = blockIdx.z;
  const bf16_t* Wt = (z == 0) ? WqT : (z == 1) ? WkT : WvT;
  const float* bias = (z == 0) ? bq : (z == 1) ? bk : bv;
  const float oscale = (z == 0) ? 0.18033688011112042f : 1.0f;  // 0.125*log2(e)

  const int tid = threadIdx.x, lane = tid & 63, w = tid >> 6;
  const int wr = w >> 1, wc = w & 1;
  const int l15 = lane & 15, quad = lane >> 4;
  const int m0 = blockIdx.y * 128, n0 = blockIdx.x * 128;

  floatx4 acc[4][4] = {};

  for (int kt = 0; kt < 768; kt += 64) {
#pragma unroll
    for (int p = 0; p < 4; ++p) {
      int c = p * 256 + tid;
      int row = c >> 3, qo = (c & 7) * 8;
      *(bf16x8*)&Al[row * LDPG + qo] = *(const bf16x8*)&Wt[(m0 + row) * 768 + kt + qo];
      *(bf16x8*)&Bl[row * LDPG + qo] = *(const bf16x8*)&Xb[(n0 + row) * 768 + kt + qo];
    }
    __syncthreads();
#pragma unroll
    for (int kk = 0; kk < 2; ++kk) {
      bf16x8 af[4], bfr[4];
#pragma unroll
      for (int i = 0; i < 4; ++i) {
        af[i]  = *(bf16x8*)&Al[(wr * 64 + i * 16 + l15) * LDPG + kk * 32 + quad * 8];
        bfr[i] = *(bf16x8*)&Bl[(wc * 64 + i * 16 + l15) * LDPG + kk * 32 + quad * 8];
      }
#pragma unroll
      for (int mi = 0; mi < 4; ++mi)
#pragma unroll
        for (int ni = 0; ni < 4; ++ni)
          acc[mi][ni] = MFMA32(af[mi], bfr[ni], acc[mi][ni]);
    }
    __syncthreads();
  }

  const int hh = (m0 + wr * 64) >> 6;  // head (64-aligned per wave-row)
#pragma unroll
  for (int mi = 0; mi < 4; ++mi) {
    const int d0 = mi * 16 + quad * 4;           // d within head, multiple of 4
    const int gm0 = m0 + wr * 64 + d0;
    float bv4[4];
#pragma unroll
    for (int r = 0; r < 4; ++r) bv4[r] = bias[gm0 + r];
#pragma unroll
    for (int ni = 0; ni < 4; ++ni) {
      const int gn = n0 + wc * 64 + ni * 16 + l15;
      const int bb = gn >> 11, tok = gn & 2047;
      const int bh = bb * 12 + hh;
      if (z == 0) {
        bf16x4 pk;
#pragma unroll
        for (int r = 0; r < 4; ++r)
          pk[r] = (bf16_t)((acc[mi][ni][r] + bv4[r]) * oscale);
        *(bf16x4*)&qw[bh * 131072 + tok * 64 + d0] = pk;
      } else if (z == 1) {
        const int kt2 = tok >> 7, k128 = tok & 127;
        const int nk = k128 >> 4, kl15 = k128 & 15;
        const int kk = d0 >> 5, kq = (d0 >> 3) & 3, j0 = d0 & 7;
        bf16x4 pk;
#pragma unroll
        for (int r = 0; r < 4; ++r)
          pk[r] = (bf16_t)(acc[mi][ni][r] + bv4[r]);
        *(bf16x4*)&kw[bh * 131072 + kt2 * 8192 +
                      ((nk * 2 + kk) * 64 + kq * 16 + kl15) * 8 + j0] = pk;
      } else {
        const int kt2 = tok >> 7, k128 = tok & 127;
        const int nk = k128 >> 4, vq = (k128 >> 2) & 3, j = k128 & 3;
        const int nd = d0 >> 4, vl0 = d0 & 15;
        const int base = bh * 131072 + kt2 * 8192 +
                         ((nk * 4 + nd) * 64 + vq * 16 + vl0) * 4 + j;
#pragma unroll
        for (int r = 0; r < 4; ++r)
          vtw[base + r * 4] = (bf16_t)(acc[mi][ni][r] + bv4[r]);
      }
    }
  }
}

// Output projection, M = channels: out fp32 [4096 tok][768 ch] via float4 stores.
__global__ __launch_bounds__(256) void gemm_proj(
    const bf16_t* __restrict__ Yb, const bf16_t* __restrict__ WpT,
    const float* __restrict__ bias, float* __restrict__ out) {
  __shared__ bf16_t Al[128 * LDPG];
  __shared__ bf16_t Bl[128 * LDPG];
  const int tid = threadIdx.x, lane = tid & 63, w = tid >> 6;
  const int wr = w >> 1, wc = w & 1;
  const int l15 = lane & 15, quad = lane >> 4;
  const int m0 = blockIdx.y * 128, n0 = blockIdx.x * 128;

  floatx4 acc[4][4] = {};

  for (int kt = 0; kt < 768; kt += 64) {
#pragma unroll
    for (int p = 0; p < 4; ++p) {
      int c = p * 256 + tid;
      int row = c >> 3, qo = (c & 7) * 8;
      *(bf16x8*)&Al[row * LDPG + qo] = *(const bf16x8*)&WpT[(m0 + row) * 768 + kt + qo];
      *(bf16x8*)&Bl[row * LDPG + qo] = *(const bf16x8*)&Yb[(n0 + row) * 768 + kt + qo];
    }
    __syncthreads();
#pragma unroll
    for (int kk = 0; kk < 2; ++kk) {
      bf16x8 af[4], bfr[4];
#pragma unroll
      for (int i = 0; i < 4; ++i) {
        af[i]  = *(bf16x8*)&Al[(wr * 64 + i * 16 + l15) * LDPG + kk * 32 + quad * 8];
        bfr[i] = *(bf16x8*)&Bl[(wc * 64 + i * 16 + l15) * LDPG + kk * 32 + quad * 8];
      }
#pragma unroll
      for (int mi = 0; mi < 4; ++mi)
#pragma unroll
        for (int ni = 0; ni < 4; ++ni)
          acc[mi][ni] = MFMA32(af[mi], bfr[ni], acc[mi][ni]);
    }
    __syncthreads();
  }

#pragma unroll
  for (int mi = 0; mi < 4; ++mi) {
    const int gm0 = m0 + wr * 64 + mi * 16 + quad * 4;
    floatx4 bv4;
#pragma unroll
    for (int r = 0; r < 4; ++r) bv4[r] = bias[gm0 + r];
#pragma unroll
    for (int ni = 0; ni < 4; ++ni) {
      const int gn = n0 + wc * 64 + ni * 16 + l15;
      floatx4 v = acc[mi][ni] + bv4;
      *(floatx4*)&out[gn * 768 + gm0] = v;
    }
  }
}

// --------------------------------------------------------------- attention --
// Block: one (b,h), 64 Q rows.  Wave w=(wk<<1)|wq: wq picks 32-q half, wk picks
// 64-key half of each 128-key tile.  K/V tiles arrive in fragment order ->
// staging is a linear copy; every frag read is lane-contiguous (0 conflicts).
// End: 2-way cross-wave O reduction (fp32) + lsum exchange via reused LDS.
__global__ __launch_bounds__(256, 4) void attn_kernel(
    const bf16_t* __restrict__ Q, const bf16_t* __restrict__ Kf,
    const bf16_t* __restrict__ Vf, bf16_t* __restrict__ Y) {
  __shared__ __align__(16) bf16_t smem[16384];  // K tile [0,8192), V tile [8192,16384)
  __shared__ float Ls[2][2][2][16];             // [wq][wk][ni][q&15]
  bf16_t* Kl = smem;
  bf16_t* Vl = smem + 8192;
  float* Ox = (float*)smem;                     // exchange region (16 KB used)

  const int tid = threadIdx.x, lane = tid & 63, w = tid >> 6;
  const int wq = w & 1, wk = w >> 1;
  const int l15 = lane & 15, quad = lane >> 4;
  const int bh = blockIdx.y;
  const int q0 = blockIdx.x * 64;
  const bf16_t* Qb = Q + bh * 131072;
  const bf16_t* Kb = Kf + bh * 131072;
  const bf16_t* Vb = Vf + bh * 131072;

  // Q B-frags (x32): n=q over l15, k=dh over quad*8+j.  32 q per wave.
  bf16x8 qf[2][2];
#pragma unroll
  for (int ni = 0; ni < 2; ++ni)
#pragma unroll
    for (int kk = 0; kk < 2; ++kk)
      qf[ni][kk] = *(const bf16x8*)&Qb[(q0 + wq * 32 + ni * 16 + l15) * 64 +
                                       kk * 32 + quad * 8];

  floatx4 oacc[2][4] = {};   // [ni(q16)][nd(d16)] partial over this wave's keys
  float lsum[2] = {0.f, 0.f};

  for (int kt = 0; kt < 16; ++kt) {
    const bf16_t* kg = Kb + kt * 8192;
    const bf16_t* vg = Vb + kt * 8192;
#pragma unroll
    for (int p = 0; p < 4; ++p) {
      const int off = (p * 256 + tid) * 8;   // linear: conflict-free b128 writes
      *(bf16x8*)&Kl[off] = *(const bf16x8*)&kg[off];
      *(bf16x8*)&Vl[off] = *(const bf16x8*)&vg[off];
    }
    __syncthreads();

    // S^T = K*Q^T for this wave's 64 keys x 32 q; then P = exp2 packed to
    // x16 A-frags (m=q=l15, k=key=quad*4+r).
    short4_t pk[4][2];
#pragma unroll
    for (int mt = 0; mt < 4; ++mt) {
      floatx4 s[2] = {};
#pragma unroll
      for (int kk = 0; kk < 2; ++kk) {
        bf16x8 kfr = *(bf16x8*)&Kl[((wk * 4 + mt) * 2 + kk) * 512 + lane * 8];
#pragma unroll
        for (int ni = 0; ni < 2; ++ni)
          s[ni] = MFMA32(kfr, qf[ni][kk], s[ni]);
      }
#pragma unroll
      for (int ni = 0; ni < 2; ++ni) {
        bf16x4 ph;
#pragma unroll
        for (int r = 0; r < 4; ++r) {
          const float pv = __builtin_amdgcn_exp2f(s[ni][r]);
          lsum[ni] += pv;
          ph[r] = (bf16_t)pv;
        }
        pk[mt][ni] = __builtin_bit_cast(short4_t, ph);
      }
    }

    // O += P*V (x16): V B-frag (k=key=quad*4+j, n=d=l15), lane-contiguous b64.
#pragma unroll
    for (int mt = 0; mt < 4; ++mt)
#pragma unroll
      for (int nd = 0; nd < 4; ++nd) {
        bf16x4 vfr = *(bf16x4*)&Vl[((wk * 4 + mt) * 4 + nd) * 256 + lane * 4];
        short4_t vs = __builtin_bit_cast(short4_t, vfr);
#pragma unroll
        for (int ni = 0; ni < 2; ++ni)
          oacc[ni][nd] = MFMA16(pk[mt][ni], vs, oacc[ni][nd]);
      }
    __syncthreads();
  }

  // lsum: reduce across quads -> every lane has this wave's total for q=ni*16+l15.
#pragma unroll
  for (int ni = 0; ni < 2; ++ni) {
    lsum[ni] += __shfl_xor(lsum[ni], 16);
    lsum[ni] += __shfl_xor(lsum[ni], 32);
  }
  if (quad == 0) {
#pragma unroll
    for (int ni = 0; ni < 2; ++ni) Ls[wq][wk][ni][l15] = lsum[ni];
  }

  // Each wave writes its NON-owned d-half (fp32, b128, conflict-free),
  // then reads partner's partial for its owned half.
#pragma unroll
  for (int ni = 0; ni < 2; ++ni)
#pragma unroll
    for (int ndl = 0; ndl < 2; ++ndl) {
      const int nd = (1 - wk) * 2 + ndl;
      *(floatx4*)&Ox[((((wq * 2 + wk) * 2 + ni) * 2 + ndl) * 64 + lane) * 4] =
          oacc[ni][nd];
    }
  __syncthreads();

  const int bb = bh / 12, h = bh % 12;
#pragma unroll
  for (int ni = 0; ni < 2; ++ni) {
    float tot[4];
#pragma unroll
    for (int r = 0; r < 4; ++r)
      tot[r] = Ls[wq][0][ni][quad * 4 + r] + Ls[wq][1][ni][quad * 4 + r];
#pragma unroll
    for (int ndl = 0; ndl < 2; ++ndl) {
      const int nd = wk * 2 + ndl;
      floatx4 o = oacc[ni][nd];
      floatx4 other =
          *(floatx4*)&Ox[((((wq * 2 + (1 - wk)) * 2 + ni) * 2 + ndl) * 64 + lane) * 4];
      o += other;
#pragma unroll
      for (int r = 0; r < 4; ++r) {
        const int tok = q0 + wq * 32 + ni * 16 + quad * 4 + r;
        const int col = h * 64 + nd * 16 + l15;
        Y[(bb * 2048 + tok) * 768 + col] = (bf16_t)(o[r] / tot[r]);
      }
    }
  }
}

// ------------------------------------------------------------------ launch --
extern "C" void kernel_launch(void* const* d_in, const int* in_sizes, int n_in,
                              void* d_out, int out_size, void* d_ws, size_t ws_size,
                              hipStream_t stream) {
  const float* x  = (const float*)d_in[0];
  const float* Wq = (const float*)d_in[1];
  const float* bq = (const float*)d_in[2];
  const float* Wk = (const float*)d_in[3];
  const float* bk = (const float*)d_in[4];
  const float* Wv = (const float*)d_in[5];
  const float* bv = (const float*)d_in[6];
  const float* Wp = (const float*)d_in[7];
  const float* bp = (const float*)d_in[8];
  float* out = (float*)d_out;

  char* ws = (char*)d_ws;
  bf16_t* xb  = (bf16_t*)ws; ws += (size_t)4096 * 768 * 2;
  bf16_t* WqT = (bf16_t*)ws; ws += (size_t)768 * 768 * 2;
  bf16_t* WkT = (bf16_t*)ws; ws += (size_t)768 * 768 * 2;
  bf16_t* WvT = (bf16_t*)ws; ws += (size_t)768 * 768 * 2;
  bf16_t* WpT = (bf16_t*)ws; ws += (size_t)768 * 768 * 2;
  bf16_t* qw  = (bf16_t*)ws; ws += (size_t)24 * 2048 * 64 * 2;
  bf16_t* kw  = (bf16_t*)ws; ws += (size_t)24 * 2048 * 64 * 2;
  bf16_t* vtw = (bf16_t*)ws; ws += (size_t)24 * 2048 * 64 * 2;
  bf16_t* yw  = (bf16_t*)ws; ws += (size_t)4096 * 768 * 2;

  cvt_x_kernel<<<3072, 256, 0, stream>>>(x, xb);
  cvt_wt_kernel<<<dim3(12, 12, 4), 256, 0, stream>>>(Wq, Wk, Wv, Wp, WqT, WkT, WvT, WpT);

  gemm_qkv<<<dim3(32, 6, 3), 256, 0, stream>>>(xb, WqT, WkT, WvT, bq, bk, bv, qw, kw, vtw);
  attn_kernel<<<dim3(32, 24), 256, 0, stream>>>(qw, kw, vtw, yw);
  gemm_proj<<<dim3(32, 6), 256, 0, stream>>>(yw, WpT, bp, out);
}